// Round 1
// baseline (594.818 us; speedup 1.0000x reference)
//
#include <hip/hip_runtime.h>

#define M_DIM 4096
#define K_DIM 4096
#define N_DIM 11008
#define BM 128
#define BN 128
#define BK 64

typedef int v4i __attribute__((ext_vector_type(4)));

__device__ __forceinline__ void load_lds16(const void* g, void* l) {
    __builtin_amdgcn_global_load_lds(
        (const __attribute__((address_space(1))) void*)g,
        (__attribute__((address_space(3))) void*)l,
        16, 0, 0);
}

// x: quint8 values in int32, subtract zero point, pack 4 -> one u32
__global__ void pack_x_kernel(const int* __restrict__ x, signed char* __restrict__ out,
                              const int* __restrict__ zp_p, int n4) {
    int i = blockIdx.x * blockDim.x + threadIdx.x;
    if (i >= n4) return;
    int zp = zp_p[0];
    int4 v = ((const int4*)x)[i];
    unsigned int p = ((unsigned int)(v.x - zp) & 0xFF)
                   | (((unsigned int)(v.y - zp) & 0xFF) << 8)
                   | (((unsigned int)(v.z - zp) & 0xFF) << 16)
                   | (((unsigned int)(v.w - zp) & 0xFF) << 24);
    ((unsigned int*)out)[i] = p;
}

// w: qint8 values in int32, pack 4 -> one u32
__global__ void pack_w_kernel(const int* __restrict__ w, signed char* __restrict__ out, int n4) {
    int i = blockIdx.x * blockDim.x + threadIdx.x;
    if (i >= n4) return;
    int4 v = ((const int4*)w)[i];
    unsigned int p = ((unsigned int)v.x & 0xFF)
                   | (((unsigned int)v.y & 0xFF) << 8)
                   | (((unsigned int)v.z & 0xFF) << 16)
                   | (((unsigned int)v.w & 0xFF) << 24);
    ((unsigned int*)out)[i] = p;
}

// C[m][n] = sum_k (x8[m][k] * w8[n][k]); epilogue dequant+bias+requant -> int32 [0,255]
__global__ __launch_bounds__(256) void gemm_i8_kernel(
    const signed char* __restrict__ A8,   // [M][K] int8 (x - zp)
    const signed char* __restrict__ B8,   // [N][K] int8 (w)
    const float* __restrict__ bias,
    const float* __restrict__ xs_p, const float* __restrict__ ws_p,
    const float* __restrict__ os_p, const int* __restrict__ ozp_p,
    int* __restrict__ out) {
    // 16B granules; swizzled: granule (row, g) stored at slot row*4 + (g ^ ((row>>2)&3))
    __shared__ v4i As[BM * BK / 16];   // 512 granules = 8 KB
    __shared__ v4i Bs[BN * BK / 16];

    const int tid  = threadIdx.x;
    const int lane = tid & 63;
    const int wave = tid >> 6;
    const int m0 = blockIdx.y * BM;
    const int n0 = blockIdx.x * BN;

    // --- staging addresses: slot s -> (row = s>>2, g = (s&3) ^ ((row>>2)&3)) ---
    const int s0 = tid, s1 = tid + 256;
    const int row0 = s0 >> 2, row1 = s1 >> 2;
    const int g0 = (s0 & 3) ^ ((row0 >> 2) & 3);
    const int g1 = (s1 & 3) ^ ((row1 >> 2) & 3);
    const long offA0 = (long)(m0 + row0) * K_DIM + g0 * 16;
    const long offA1 = (long)(m0 + row1) * K_DIM + g1 * 16;
    const long offB0 = (long)(n0 + row0) * K_DIM + g0 * 16;
    const long offB1 = (long)(n0 + row1) * K_DIM + g1 * 16;
    char* ldsA0 = (char*)As + s0 * 16;
    char* ldsA1 = (char*)As + s1 * 16;
    char* ldsB0 = (char*)Bs + s0 * 16;
    char* ldsB1 = (char*)Bs + s1 * 16;

    // --- fragment slots ---
    const int waveM = wave >> 1, waveN = wave & 1;
    const int l15 = lane & 15, quad = lane >> 4;
    const int sw = l15 >> 2;                 // ((m_loc>>2)&3) for any mt since tiles are 16-aligned
    int aSlot[4], bSlot[4];
#pragma unroll
    for (int t = 0; t < 4; ++t) {
        aSlot[t] = (waveM * 64 + t * 16 + l15) * 4 + (quad ^ sw);
        bSlot[t] = (waveN * 64 + t * 16 + l15) * 4 + (quad ^ sw);
    }

    v4i acc[4][4];
#pragma unroll
    for (int mt = 0; mt < 4; ++mt)
#pragma unroll
        for (int nt = 0; nt < 4; ++nt) {
            v4i z = {0, 0, 0, 0};
            acc[mt][nt] = z;
        }

    for (int k0 = 0; k0 < K_DIM; k0 += BK) {
        load_lds16(A8 + offA0 + k0, ldsA0);
        load_lds16(A8 + offA1 + k0, ldsA1);
        load_lds16(B8 + offB0 + k0, ldsB0);
        load_lds16(B8 + offB1 + k0, ldsB1);
        __syncthreads();   // drains vmcnt(0): global_load_lds writes visible

        v4i a[4], b[4];
#pragma unroll
        for (int t = 0; t < 4; ++t) a[t] = As[aSlot[t]];
#pragma unroll
        for (int t = 0; t < 4; ++t) b[t] = Bs[bSlot[t]];
#pragma unroll
        for (int mt = 0; mt < 4; ++mt)
#pragma unroll
            for (int nt = 0; nt < 4; ++nt)
                acc[mt][nt] = __builtin_amdgcn_mfma_i32_16x16x64_i8(
                    a[mt], b[nt], acc[mt][nt], 0, 0, 0);
        __syncthreads();   // LDS consumed; safe to overwrite next iter
    }

    // --- epilogue: dequant + bias, requant to [0,255] int ---
    const float scale  = xs_p[0] * ws_p[0];
    const float inv_os = 1.0f / os_p[0];
    const int   ozp    = ozp_p[0];
#pragma unroll
    for (int mt = 0; mt < 4; ++mt) {
        const int rbase = m0 + waveM * 64 + mt * 16 + quad * 4;
#pragma unroll
        for (int nt = 0; nt < 4; ++nt) {
            const int col = n0 + waveN * 64 + nt * 16 + l15;
            const float bv = bias[col];
#pragma unroll
            for (int r = 0; r < 4; ++r) {
                float y = (float)acc[mt][nt][r] * scale + bv;
                int q = (int)rintf(y * inv_os) + ozp;
                q = q < 0 ? 0 : (q > 255 ? 255 : q);
                out[(long)(rbase + r) * N_DIM + col] = q;
            }
        }
    }
}

extern "C" void kernel_launch(void* const* d_in, const int* in_sizes, int n_in,
                              void* d_out, int out_size, void* d_ws, size_t ws_size,
                              hipStream_t stream) {
    const int*   x_q  = (const int*)d_in[0];
    const int*   w_q  = (const int*)d_in[1];
    const float* bias = (const float*)d_in[2];
    const float* xs   = (const float*)d_in[3];
    const float* wsc  = (const float*)d_in[4];
    const float* os   = (const float*)d_in[5];
    const int*   xzp  = (const int*)d_in[6];
    const int*   ozp  = (const int*)d_in[7];

    signed char* x8 = (signed char*)d_ws;                               // 16 MB
    signed char* w8 = (signed char*)d_ws + (size_t)M_DIM * K_DIM;       // 45 MB

    const int nx4 = M_DIM * K_DIM / 4;
    pack_x_kernel<<<(nx4 + 255) / 256, 256, 0, stream>>>(x_q, x8, xzp, nx4);
    const int nw4 = N_DIM * K_DIM / 4;
    pack_w_kernel<<<(nw4 + 255) / 256, 256, 0, stream>>>(w_q, w8, nw4);

    dim3 grid(N_DIM / BN, M_DIM / BM);
    gemm_i8_kernel<<<grid, 256, 0, stream>>>(x8, w8, bias, xs, wsc, os, ozp, (int*)d_out);
}

// Round 2
// 565.921 us; speedup vs baseline: 1.0511x; 1.0511x over previous
//
#include <hip/hip_runtime.h>

#define M_DIM 4096
#define K_DIM 4096
#define N_DIM 11008
#define BM 128
#define BN 128
#define BK 128   // bytes of K per tile iteration (int8)

typedef int v4i __attribute__((ext_vector_type(4)));

__device__ __forceinline__ void load_lds16(const void* g, void* l) {
    __builtin_amdgcn_global_load_lds(
        (const __attribute__((address_space(1))) void*)g,
        (__attribute__((address_space(3))) void*)l,
        16, 0, 0);
}

// x: quint8 values in int32, subtract zero point, pack 4 -> one u32
__global__ void pack_x_kernel(const int* __restrict__ x, signed char* __restrict__ out,
                              const int* __restrict__ zp_p, int n4) {
    int i = blockIdx.x * blockDim.x + threadIdx.x;
    if (i >= n4) return;
    int zp = zp_p[0];
    int4 v = ((const int4*)x)[i];
    unsigned int p = ((unsigned int)(v.x - zp) & 0xFF)
                   | (((unsigned int)(v.y - zp) & 0xFF) << 8)
                   | (((unsigned int)(v.z - zp) & 0xFF) << 16)
                   | (((unsigned int)(v.w - zp) & 0xFF) << 24);
    ((unsigned int*)out)[i] = p;
}

// w: qint8 values in int32, pack 4 -> one u32
__global__ void pack_w_kernel(const int* __restrict__ w, signed char* __restrict__ out, int n4) {
    int i = blockIdx.x * blockDim.x + threadIdx.x;
    if (i >= n4) return;
    int4 v = ((const int4*)w)[i];
    unsigned int p = ((unsigned int)v.x & 0xFF)
                   | (((unsigned int)v.y & 0xFF) << 8)
                   | (((unsigned int)v.z & 0xFF) << 16)
                   | (((unsigned int)v.w & 0xFF) << 24);
    ((unsigned int*)out)[i] = p;
}

// C[m][n] = sum_k (x8[m][k] * w8[n][k]); epilogue dequant+bias+requant -> int32 [0,255]
// LDS layout: 16B granules. Row stride = BK/16 = 8 granules (128B = exact bank wrap),
// so granule g of row r is stored at slot r*8 + (g ^ (r&7)) -> fragment reads are
// 2-way per bank phase (free per m136), staging writes stay lane-contiguous.
__global__ __launch_bounds__(256) void gemm_i8_kernel(
    const signed char* __restrict__ A8,   // [M][K] int8 (x - zp)
    const signed char* __restrict__ B8,   // [N][K] int8 (w)
    const float* __restrict__ bias,
    const float* __restrict__ xs_p, const float* __restrict__ ws_p,
    const float* __restrict__ os_p, const int* __restrict__ ozp_p,
    int* __restrict__ out) {
    __shared__ v4i As[BM * BK / 16];   // 1024 granules = 16 KB
    __shared__ v4i Bs[BN * BK / 16];   // 16 KB

    const int tid  = threadIdx.x;
    const int lane = tid & 63;
    const int wave = tid >> 6;

    // ---- XCD-aware block swizzle ----
    // xcd = bid & 7 owns m-band [xcd*4, xcd*4+4); within the band, 4x4 chunks of
    // (m,n) blocks with m fastest (B-slab reused 4x back-to-back, A-band L2-resident).
    const int bid   = blockIdx.x;
    const int xcd   = bid & 7;
    const int local = bid >> 3;           // [0, 344)
    const int m_blk = xcd * 4 + (local & 3);
    const int n_blk = (local >> 4) * 4 + ((local & 15) >> 2);
    const int m0 = m_blk * BM;
    const int n0 = n_blk * BN;

    // ---- staging addresses: 8 granules per thread (4 A + 4 B) ----
    long offA[4], offB[4];
    char *ldsA[4], *ldsB[4];
#pragma unroll
    for (int j = 0; j < 4; ++j) {
        const int s   = tid + 256 * j;    // slot
        const int row = s >> 3;
        const int gg  = (s & 7) ^ (row & 7);  // global granule stored at this slot
        offA[j] = (long)(m0 + row) * K_DIM + gg * 16;
        offB[j] = (long)(n0 + row) * K_DIM + gg * 16;
        ldsA[j] = (char*)As + s * 16;
        ldsB[j] = (char*)Bs + s * 16;
    }

    // ---- fragment slots ----
    const int waveM = wave >> 1, waveN = wave & 1;
    const int l15 = lane & 15, quad = lane >> 4;
    int aSlot[4][2], bSlot[4][2];
#pragma unroll
    for (int t = 0; t < 4; ++t) {
#pragma unroll
        for (int ks = 0; ks < 2; ++ks) {
            const int g = ks * 4 + quad;
            aSlot[t][ks] = (waveM * 64 + t * 16 + l15) * 8 + (g ^ (l15 & 7));
            bSlot[t][ks] = (waveN * 64 + t * 16 + l15) * 8 + (g ^ (l15 & 7));
        }
    }

    v4i acc[4][4];
#pragma unroll
    for (int mt = 0; mt < 4; ++mt)
#pragma unroll
        for (int nt = 0; nt < 4; ++nt) {
            v4i z = {0, 0, 0, 0};
            acc[mt][nt] = z;
        }

    for (int k0 = 0; k0 < K_DIM; k0 += BK) {
#pragma unroll
        for (int j = 0; j < 4; ++j) load_lds16(A8 + offA[j] + k0, ldsA[j]);
#pragma unroll
        for (int j = 0; j < 4; ++j) load_lds16(B8 + offB[j] + k0, ldsB[j]);
        __syncthreads();   // drains vmcnt(0): all 8 loads land together

#pragma unroll
        for (int ks = 0; ks < 2; ++ks) {
            v4i a[4], b[4];
#pragma unroll
            for (int t = 0; t < 4; ++t) a[t] = As[aSlot[t][ks]];
#pragma unroll
            for (int t = 0; t < 4; ++t) b[t] = Bs[bSlot[t][ks]];
#pragma unroll
            for (int mt = 0; mt < 4; ++mt)
#pragma unroll
                for (int nt = 0; nt < 4; ++nt)
                    acc[mt][nt] = __builtin_amdgcn_mfma_i32_16x16x64_i8(
                        a[mt], b[nt], acc[mt][nt], 0, 0, 0);
        }
        __syncthreads();   // LDS consumed; safe to overwrite next iter
    }

    // ---- epilogue: dequant + bias, requant to [0,255] int ----
    const float scale  = xs_p[0] * ws_p[0];
    const float inv_os = 1.0f / os_p[0];
    const int   ozp    = ozp_p[0];
#pragma unroll
    for (int mt = 0; mt < 4; ++mt) {
        const int rbase = m0 + waveM * 64 + mt * 16 + quad * 4;
#pragma unroll
        for (int nt = 0; nt < 4; ++nt) {
            const int col = n0 + waveN * 64 + nt * 16 + l15;
            const float bv = bias[col];
#pragma unroll
            for (int r = 0; r < 4; ++r) {
                float y = (float)acc[mt][nt][r] * scale + bv;
                int q = (int)rintf(y * inv_os) + ozp;
                q = q < 0 ? 0 : (q > 255 ? 255 : q);
                out[(long)(rbase + r) * N_DIM + col] = q;
            }
        }
    }
}

extern "C" void kernel_launch(void* const* d_in, const int* in_sizes, int n_in,
                              void* d_out, int out_size, void* d_ws, size_t ws_size,
                              hipStream_t stream) {
    const int*   x_q  = (const int*)d_in[0];
    const int*   w_q  = (const int*)d_in[1];
    const float* bias = (const float*)d_in[2];
    const float* xs   = (const float*)d_in[3];
    const float* wsc  = (const float*)d_in[4];
    const float* os   = (const float*)d_in[5];
    const int*   xzp  = (const int*)d_in[6];
    const int*   ozp  = (const int*)d_in[7];

    signed char* x8 = (signed char*)d_ws;                               // 16 MB
    signed char* w8 = (signed char*)d_ws + (size_t)M_DIM * K_DIM;       // 45 MB

    const int nx4 = M_DIM * K_DIM / 4;
    pack_x_kernel<<<(nx4 + 255) / 256, 256, 0, stream>>>(x_q, x8, xzp, nx4);
    const int nw4 = N_DIM * K_DIM / 4;
    pack_w_kernel<<<(nw4 + 255) / 256, 256, 0, stream>>>(w_q, w8, nw4);

    // 1D grid: 2752 blocks = 8 XCD-bands x (4 m-blocks x 86 n-blocks)
    const int nblocks = (M_DIM / BM) * (N_DIM / BN);
    gemm_i8_kernel<<<nblocks, 256, 0, stream>>>(x8, w8, bias, xs, wsc, os, ozp, (int*)d_out);
}

// Round 3
// 519.749 us; speedup vs baseline: 1.1444x; 1.0888x over previous
//
#include <hip/hip_runtime.h>

#define M_DIM 4096
#define K_DIM 4096
#define N_DIM 11008
#define BM 128
#define BN 128
#define BK 128   // bytes of K per tile iteration (int8)
#define NTILES (K_DIM / BK)   // 32

typedef int v4i  __attribute__((ext_vector_type(4)));
typedef int v16i __attribute__((ext_vector_type(16)));

// s_waitcnt immediates (gfx90a+ encoding: vmcnt[3:0]+[15:14], exp[6:4], lgkm[13:8])
#define WAIT_VM8 0x3F78   // vmcnt<=8, exp/lgkm unconstrained
#define WAIT_VM0 0x3F70   // vmcnt<=0

__device__ __forceinline__ void load_lds16(const void* g, void* l) {
    __builtin_amdgcn_global_load_lds(
        (const __attribute__((address_space(1))) void*)g,
        (__attribute__((address_space(3))) void*)l,
        16, 0, 0);
}

__global__ void pack_x_kernel(const int* __restrict__ x, signed char* __restrict__ out,
                              const int* __restrict__ zp_p, int n4) {
    int i = blockIdx.x * blockDim.x + threadIdx.x;
    if (i >= n4) return;
    int zp = zp_p[0];
    int4 v = ((const int4*)x)[i];
    unsigned int p = ((unsigned int)(v.x - zp) & 0xFF)
                   | (((unsigned int)(v.y - zp) & 0xFF) << 8)
                   | (((unsigned int)(v.z - zp) & 0xFF) << 16)
                   | (((unsigned int)(v.w - zp) & 0xFF) << 24);
    ((unsigned int*)out)[i] = p;
}

__global__ void pack_w_kernel(const int* __restrict__ w, signed char* __restrict__ out, int n4) {
    int i = blockIdx.x * blockDim.x + threadIdx.x;
    if (i >= n4) return;
    int4 v = ((const int4*)w)[i];
    unsigned int p = ((unsigned int)v.x & 0xFF)
                   | (((unsigned int)v.y & 0xFF) << 8)
                   | (((unsigned int)v.z & 0xFF) << 16)
                   | (((unsigned int)v.w & 0xFF) << 24);
    ((unsigned int*)out)[i] = p;
}

// LDS tile layout (per buffer): row-major, row stride 8 granules of 16B;
// granule g of row r stored at slot r*8 + (g ^ (r&7))  -> conflict-free (0 measured R2).
__global__ __launch_bounds__(256) void gemm_i8_kernel(
    const signed char* __restrict__ A8,   // [M][K] int8 (x - zp)
    const signed char* __restrict__ B8,   // [N][K] int8 (w)
    const float* __restrict__ bias,
    const float* __restrict__ xs_p, const float* __restrict__ ws_p,
    const float* __restrict__ os_p, const int* __restrict__ ozp_p,
    int* __restrict__ out) {
    __shared__ v4i As0[BM * BK / 16];   // 16 KB each
    __shared__ v4i Bs0[BN * BK / 16];
    __shared__ v4i As1[BM * BK / 16];
    __shared__ v4i Bs1[BN * BK / 16];

    const int tid  = threadIdx.x;
    const int lane = tid & 63;
    const int wave = tid >> 6;

    // ---- XCD-aware block swizzle (validated R2) ----
    const int bid   = blockIdx.x;
    const int xcd   = bid & 7;
    const int local = bid >> 3;           // [0, 344)
    const int m_blk = xcd * 4 + (local & 3);
    const int n_blk = (local >> 4) * 4 + ((local & 15) >> 2);
    const int m0 = m_blk * BM;
    const int n0 = n_blk * BN;

    // ---- staging addresses: 8 granules per thread (4 A + 4 B) per tile ----
    long offA[4], offB[4];
    int  ldsOff[4];
#pragma unroll
    for (int j = 0; j < 4; ++j) {
        const int s   = tid + 256 * j;
        const int row = s >> 3;
        const int gg  = (s & 7) ^ (row & 7);
        offA[j]   = (long)(m0 + row) * K_DIM + gg * 16;
        offB[j]   = (long)(n0 + row) * K_DIM + gg * 16;
        ldsOff[j] = s;   // v4i slot
    }

    // ---- fragment slots for mfma_i32_32x32x32_i8 ----
    // A/B operand: m(or n) = lane&31, k bytes [(lane>>5)*16, +16)
    const int waveM = wave >> 1, waveN = wave & 1;
    const int l31 = lane & 31, h = lane >> 5;
    int aSlot[2][4], bSlot[2][4];
#pragma unroll
    for (int t = 0; t < 2; ++t) {
        const int rA = waveM * 64 + t * 32 + l31;
        const int rB = waveN * 64 + t * 32 + l31;
#pragma unroll
        for (int s = 0; s < 4; ++s) {
            const int g = 2 * s + h;
            aSlot[t][s] = rA * 8 + (g ^ (rA & 7));
            bSlot[t][s] = rB * 8 + (g ^ (rB & 7));
        }
    }

    v16i acc[2][2];
#pragma unroll
    for (int mt = 0; mt < 2; ++mt)
#pragma unroll
        for (int nt = 0; nt < 2; ++nt)
#pragma unroll
            for (int r = 0; r < 16; ++r) acc[mt][nt][r] = 0;

    // ---- helpers ----
    auto stage = [&](int tile, v4i* Asb, v4i* Bsb) {
        const long koff = (long)tile * BK;
#pragma unroll
        for (int j = 0; j < 4; ++j) load_lds16(A8 + offA[j] + koff, (char*)(Asb + ldsOff[j]));
#pragma unroll
        for (int j = 0; j < 4; ++j) load_lds16(B8 + offB[j] + koff, (char*)(Bsb + ldsOff[j]));
    };
    auto compute = [&](const v4i* Asb, const v4i* Bsb) {
#pragma unroll
        for (int s = 0; s < 4; ++s) {
            v4i a[2], b[2];
#pragma unroll
            for (int t = 0; t < 2; ++t) a[t] = Asb[aSlot[t][s]];
#pragma unroll
            for (int t = 0; t < 2; ++t) b[t] = Bsb[bSlot[t][s]];
#pragma unroll
            for (int mt = 0; mt < 2; ++mt)
#pragma unroll
                for (int nt = 0; nt < 2; ++nt)
                    acc[mt][nt] = __builtin_amdgcn_mfma_i32_32x32x32_i8(
                        a[mt], b[nt], acc[mt][nt], 0, 0, 0);
        }
    };

    // ---- async double-buffered pipeline ----
    stage(0, As0, Bs0);          // 8 vm-ops in flight
    stage(1, As1, Bs1);          // 16 in flight

#pragma unroll 1
    for (int kk = 0; kk < 15; ++kk) {
        const int k = 2 * kk;
        // even: consume buf0
        __builtin_amdgcn_s_waitcnt(WAIT_VM8);   // tile k done; tile k+1 still flying
        __builtin_amdgcn_s_barrier();
        compute(As0, Bs0);
        __builtin_amdgcn_s_barrier();           // everyone done reading buf0
        stage(k + 2, As0, Bs0);
        // odd: consume buf1
        __builtin_amdgcn_s_waitcnt(WAIT_VM8);   // tile k+1 done; tile k+2 flying
        __builtin_amdgcn_s_barrier();
        compute(As1, Bs1);
        __builtin_amdgcn_s_barrier();           // everyone done reading buf1
        stage(k + 3, As1, Bs1);
    }
    // peeled tail: tiles 30, 31
    __builtin_amdgcn_s_waitcnt(WAIT_VM8);
    __builtin_amdgcn_s_barrier();
    compute(As0, Bs0);
    __builtin_amdgcn_s_waitcnt(WAIT_VM0);
    __builtin_amdgcn_s_barrier();
    compute(As1, Bs1);

    // ---- epilogue: dequant + bias, requant to [0,255] ----
    // C/D 32x32: col = lane&31, row = (reg&3) + 8*(reg>>2) + 4*(lane>>5)
    const float scale  = xs_p[0] * ws_p[0];
    const float inv_os = 1.0f / os_p[0];
    const int   ozp    = ozp_p[0];
#pragma unroll
    for (int mt = 0; mt < 2; ++mt) {
        const int rbase = m0 + waveM * 64 + mt * 32 + 4 * h;
#pragma unroll
        for (int nt = 0; nt < 2; ++nt) {
            const int col = n0 + waveN * 64 + nt * 32 + l31;
            const float bv = bias[col];
#pragma unroll
            for (int r = 0; r < 16; ++r) {
                const int row = rbase + (r & 3) + 8 * (r >> 2);
                float y = (float)acc[mt][nt][r] * scale + bv;
                int q = (int)rintf(y * inv_os) + ozp;
                q = q < 0 ? 0 : (q > 255 ? 255 : q);
                out[(long)row * N_DIM + col] = q;
            }
        }
    }
}

extern "C" void kernel_launch(void* const* d_in, const int* in_sizes, int n_in,
                              void* d_out, int out_size, void* d_ws, size_t ws_size,
                              hipStream_t stream) {
    const int*   x_q  = (const int*)d_in[0];
    const int*   w_q  = (const int*)d_in[1];
    const float* bias = (const float*)d_in[2];
    const float* xs   = (const float*)d_in[3];
    const float* wsc  = (const float*)d_in[4];
    const float* os   = (const float*)d_in[5];
    const int*   xzp  = (const int*)d_in[6];
    const int*   ozp  = (const int*)d_in[7];

    signed char* x8 = (signed char*)d_ws;                               // 16 MB
    signed char* w8 = (signed char*)d_ws + (size_t)M_DIM * K_DIM;       // 45 MB

    const int nx4 = M_DIM * K_DIM / 4;
    pack_x_kernel<<<(nx4 + 255) / 256, 256, 0, stream>>>(x_q, x8, xzp, nx4);
    const int nw4 = N_DIM * K_DIM / 4;
    pack_w_kernel<<<(nw4 + 255) / 256, 256, 0, stream>>>(w_q, w8, nw4);

    const int nblocks = (M_DIM / BM) * (N_DIM / BN);   // 2752
    gemm_i8_kernel<<<nblocks, 256, 0, stream>>>(x8, w8, bias, xs, wsc, os, ozp, (int*)d_out);
}